// Round 12
// baseline (282.869 us; speedup 1.0000x reference)
//
#include <hip/hip_runtime.h>
#include <math.h>

#define NB 16
#define CIN 128
#define COUT 128
#define SDIM 512
#define HH 128
#define WW 128

typedef __bf16 bf16x8 __attribute__((ext_vector_type(8)));
typedef float f32x16 __attribute__((ext_vector_type(16)));

static constexpr size_t WA_OFF = 8192;                          // after s (2048 f32)
static constexpr size_t WA_ELEMS = (size_t)NB * 9 * COUT * CIN; // 2,359,296 bf16
static constexpr size_t XT_OFF = WA_OFF + WA_ELEMS * 2;
static constexpr size_t XT_ELEMS = (size_t)NB * 130 * 130 * CIN;
static constexpr size_t WS_NEEDED = XT_OFF + XT_ELEMS * 2;

__device__ __forceinline__ unsigned short f32_bf16(float f) {
  unsigned int x = __float_as_uint(f);
  x += 0x7fffu + ((x >> 16) & 1u);
  return (unsigned short)(x >> 16);
}

__device__ __forceinline__ void gl_lds16(const void* g, void* l) {
  __builtin_amdgcn_global_load_lds((const __attribute__((address_space(1))) void*)g,
                                   (__attribute__((address_space(3))) void*)l, 16, 0, 0);
}

// ---------------- K0: s[b][cin] = style[b] . mod_w[cin] ----------------
__global__ void k_style(const float* __restrict__ style, const float* __restrict__ mod_w,
                        float* __restrict__ s) {
  int b = blockIdx.x, ci = threadIdx.x;
  const float4* st = (const float4*)(style + (size_t)b * SDIM);
  const float4* mw = (const float4*)(mod_w + (size_t)ci * SDIM);
  float acc = 0.f;
  for (int i = 0; i < SDIM / 4; ++i) {
    float4 a = st[i], m = mw[i];
    acc += a.x * m.x + a.y * m.y + a.z * m.z + a.w * m.w;
  }
  s[b * CIN + ci] = acc;
}

// ---------------- K1: demod + wA[b][tap][cout][cin] (bf16) ----------------
__global__ void k_wprep(const float* __restrict__ weight, const float* __restrict__ s,
                        unsigned short* __restrict__ wA) {
  int co = blockIdx.x, b = blockIdx.y, ci = threadIdx.x;
  const float scale = 0.029462782549439483f; // 1/sqrt(128*9)
  float sv = s[b * CIN + ci];
  const float* wp = weight + ((size_t)co * CIN + ci) * 9;
  float u[9], ss = 0.f;
#pragma unroll
  for (int t = 0; t < 9; ++t) { u[t] = scale * wp[t] * sv; ss += u[t] * u[t]; }
#pragma unroll
  for (int off = 32; off; off >>= 1) ss += __shfl_down(ss, off, 64);
  __shared__ float red[2];
  if ((threadIdx.x & 63) == 0) red[threadIdx.x >> 6] = ss;
  __syncthreads();
  float demod = rsqrtf(red[0] + red[1] + 1e-8f);
#pragma unroll
  for (int t = 0; t < 9; ++t)
    wA[((size_t)(b * 9 + t) * COUT + co) * CIN + ci] = f32_bf16(u[t] * demod);
}

// ---------------- K2: xt[b][hb][wb][cin] transpose, halo written in-kernel ----
__global__ void k_xt(const float* __restrict__ x, unsigned short* __restrict__ xt) {
  int hb = blockIdx.x, b = blockIdx.y;
  int t = threadIdx.x;
  unsigned short* orow = xt + ((size_t)b * 130 + hb) * 130 * CIN;
  if (hb == 0 || hb == 129) {
    uint4 z = {0u, 0u, 0u, 0u};
    for (int u = t; u < 2080; u += 256) ((uint4*)orow)[u] = z;
    return;
  }
  __shared__ unsigned short lds[128][132]; // [w][c]
  int h = hb - 1;
  const float* xrow = x + (size_t)b * CIN * HH * WW + (size_t)h * WW;
  for (int i = 0; i < 32; ++i) {
    int flat = i * 256 + t;
    int w = flat & 127, cp = flat >> 7;
    float a0 = xrow[(size_t)(2 * cp) * HH * WW + w];
    float a1 = xrow[(size_t)(2 * cp + 1) * HH * WW + w];
    unsigned int pk = (unsigned int)f32_bf16(a0) | ((unsigned int)f32_bf16(a1) << 16);
    *(unsigned int*)&lds[w][2 * cp] = pk;
  }
  __syncthreads();
  if (t < 32) {
    int side = t >> 4, g = t & 15;
    uint4 z = {0u, 0u, 0u, 0u};
    ((uint4*)(orow + (side ? (size_t)129 * CIN : 0)))[g] = z;
  }
  for (int i = 0; i < 8; ++i) {
    int u = i * 256 + t;
    int w = u >> 4, cg = u & 15;
    uint2 v0 = *(const uint2*)&lds[w][cg * 8];
    uint2 v1 = *(const uint2*)&lds[w][cg * 8 + 4];
    uint4 v = {v0.x, v0.y, v1.x, v1.y};
    *(uint4*)(orow + (size_t)(1 + w) * CIN + cg * 8) = v;
  }
}

// ---------------- K3: conv via 9 shifted GEMMs, 32x32x16 MFMA ----------------
// grid (64,NB) b-major, 512 thr = 8 waves (2 wm x 4 wn), block tile
// 128 cout x 16x16 px (r2/r9 clean envelope: 512 resident blocks, b-span 8;
// LDS padded to 57.6KB -> hard cap 2 blocks/CU). Wave = M64 x N64 via
// 32x32x16 MFMA: acc = 4 x f32x16 = 64 VGPR -> 4 waves/SIMD (2x r9 TLP);
// per tap: 4 A-loads + 4 ds_read_b128 + 8 MFMA (ds and issue per FLOP halved).
// LDS layout [row][g][col] (16B units), source-permuted staging (validated r11);
// B-read lane stride 16B = conflict-free.
// C/D map (HW-verified m74/m101): col=lane&31, row=(reg&3)+8*(reg>>2)+4*(lane>>5).
__launch_bounds__(512, 4)
__global__ void k_conv(const unsigned short* __restrict__ xt,
                       const unsigned short* __restrict__ wA,
                       const float* __restrict__ noise,
                       const float* __restrict__ nw,
                       float* __restrict__ out) {
  __shared__ uint4 ldsraw[2][1800]; // 1296 used/buffer; padded -> 57.6KB/block
  int b = blockIdx.y;
  int tile = blockIdx.x;
  int th = (tile >> 3) * 16, tw = (tile & 7) * 16;
  int t = threadIdx.x;
  int lane = t & 63, wv = t >> 6;
  int wm = wv >> 2, wn = wv & 3;      // wm: cout 64-half, wn: 4-row band
  int l31 = lane & 31, hi = lane >> 5; // A-row / B-col lane, k-group
  int l15 = lane & 15, h4 = (lane >> 4) & 1; // B: x within row, row parity

  f32x16 acc[2][2]; // [mt][nt]
#pragma unroll
  for (int mt = 0; mt < 2; ++mt)
#pragma unroll
    for (int nt = 0; nt < 2; ++nt)
#pragma unroll
      for (int r = 0; r < 16; ++r) acc[mt][nt][r] = 0.f;

  const unsigned short* xtile = xt + ((size_t)b * 130 + th) * 130 * CIN + (size_t)tw * CIN;
  const unsigned short* wbase = wA + (size_t)b * 9 * COUT * CIN
                                + (size_t)(wm * 64 + l31) * CIN + hi * 8;

  // staging source offsets for [row][g][col] LDS layout (r11-validated):
  // linear unit u = row*72 + g*18 + col holds cell (row,col), cin-group g
  int goff[3];
#pragma unroll
  for (int i = 0; i < 3; ++i) {
    int u = i * 512 + t;
    int row = u / 72, rem = u - row * 72;
    int g = rem / 18, col = rem - g * 18;
    goff[i] = (row * 130 + col) * CIN + g * 8;
  }
  int ldsslot = wv * 64;

  auto STAGE = [&](int bb, int q) {
    const unsigned short* xq = xtile + q * 32;
#pragma unroll
    for (int i = 0; i < 3; ++i) {
      int u = i * 512 + t;
      if (u < 1296)
        gl_lds16(xq + goff[i], &ldsraw[bb][i * 512 + ldsslot]);
    }
  };

  STAGE(0, 0);
  __syncthreads();

  for (int q = 0; q < 4; ++q) {
    if (q < 3) STAGE((q + 1) & 1, q + 1); // issue next-chunk x loads BEFORE compute
    const bf16x8* bb_lds = (const bf16x8*)&ldsraw[q & 1][0];
    const unsigned short* wq = wbase + (size_t)q * 32;
#pragma unroll
    for (int ky = 0; ky < 3; ++ky) {
#pragma unroll
      for (int kx = 0; kx < 3; ++kx) {
        int tap = ky * 3 + kx;
        const unsigned short* wt = wq + (size_t)tap * COUT * CIN;
        // A fragments: [mt][kstep], row = wm*64+mt*32+l31, k = kstep*16+hi*8
        bf16x8 a00 = *(const bf16x8*)(wt);
        bf16x8 a01 = *(const bf16x8*)(wt + 16);
        bf16x8 a10 = *(const bf16x8*)(wt + 32 * CIN);
        bf16x8 a11 = *(const bf16x8*)(wt + 32 * CIN + 16);
        // B fragments: [nt][kstep], imgrow = wn*4+nt*2+h4+ky, x = l15+kx,
        // g = kstep*2+hi ; unit = (imgrow*4+g)*18 + x
        int r0 = wn * 4 + h4 + ky;
        int c0 = l15 + kx;
        bf16x8 b00 = bb_lds[((r0)     * 4 + hi)     * 18 + c0];
        bf16x8 b01 = bb_lds[((r0)     * 4 + 2 + hi) * 18 + c0];
        bf16x8 b10 = bb_lds[((r0 + 2) * 4 + hi)     * 18 + c0];
        bf16x8 b11 = bb_lds[((r0 + 2) * 4 + 2 + hi) * 18 + c0];
        acc[0][0] = __builtin_amdgcn_mfma_f32_32x32x16_bf16(a00, b00, acc[0][0], 0, 0, 0);
        acc[0][0] = __builtin_amdgcn_mfma_f32_32x32x16_bf16(a01, b01, acc[0][0], 0, 0, 0);
        acc[0][1] = __builtin_amdgcn_mfma_f32_32x32x16_bf16(a00, b10, acc[0][1], 0, 0, 0);
        acc[0][1] = __builtin_amdgcn_mfma_f32_32x32x16_bf16(a01, b11, acc[0][1], 0, 0, 0);
        acc[1][0] = __builtin_amdgcn_mfma_f32_32x32x16_bf16(a10, b00, acc[1][0], 0, 0, 0);
        acc[1][0] = __builtin_amdgcn_mfma_f32_32x32x16_bf16(a11, b01, acc[1][0], 0, 0, 0);
        acc[1][1] = __builtin_amdgcn_mfma_f32_32x32x16_bf16(a10, b10, acc[1][1], 0, 0, 0);
        acc[1][1] = __builtin_amdgcn_mfma_f32_32x32x16_bf16(a11, b11, acc[1][1], 0, 0, 0);
      }
    }
    __syncthreads();
  }

  // ---- epilogue: + noise_weight[cout]*noise, store fp32 (4x64B runs/instr) ----
#pragma unroll
  for (int nt = 0; nt < 2; ++nt) {
    int hh = th + wn * 4 + nt * 2 + h4;
    int ww = tw + l15;
    float nv = noise[((size_t)b * HH + hh) * WW + ww];
#pragma unroll
    for (int mt = 0; mt < 2; ++mt) {
#pragma unroll
      for (int r = 0; r < 16; ++r) {
        int cout = wm * 64 + mt * 32 + (r & 3) + 8 * (r >> 2) + 4 * hi;
        out[(((size_t)b * COUT + cout) * HH + hh) * WW + ww] =
            acc[mt][nt][r] + nw[cout] * nv;
      }
    }
  }
}

extern "C" void kernel_launch(void* const* d_in, const int* in_sizes, int n_in,
                              void* d_out, int out_size, void* d_ws, size_t ws_size,
                              hipStream_t stream) {
  const float* x      = (const float*)d_in[0];
  const float* style  = (const float*)d_in[1];
  const float* noise  = (const float*)d_in[2];
  const float* weight = (const float*)d_in[3];
  const float* mod_w  = (const float*)d_in[4];
  const float* nw     = (const float*)d_in[5];
  float* out = (float*)d_out;
  char* ws = (char*)d_ws;
  if (ws_size < WS_NEEDED) return;

  float* s = (float*)ws;
  unsigned short* wA = (unsigned short*)(ws + WA_OFF);
  unsigned short* xt = (unsigned short*)(ws + XT_OFF);

  k_style<<<dim3(NB), dim3(CIN), 0, stream>>>(style, mod_w, s);
  k_wprep<<<dim3(COUT, NB), dim3(CIN), 0, stream>>>(weight, s, wA);
  k_xt<<<dim3(130, NB), dim3(256), 0, stream>>>(x, xt);
  k_conv<<<dim3(64, NB), dim3(512), 0, stream>>>(xt, wA, noise, nw, out);
}

// Round 13
// 276.426 us; speedup vs baseline: 1.0233x; 1.0233x over previous
//
#include <hip/hip_runtime.h>
#include <math.h>

#define NB 16
#define CIN 128
#define COUT 128
#define SDIM 512
#define HH 128
#define WW 128

typedef __bf16 bf16x8 __attribute__((ext_vector_type(8)));
typedef float f32x16 __attribute__((ext_vector_type(16)));

static constexpr size_t WA_OFF = 8192;                          // after s (2048 f32)
static constexpr size_t WA_ELEMS = (size_t)NB * 9 * COUT * CIN; // 2,359,296 bf16
static constexpr size_t XT_OFF = WA_OFF + WA_ELEMS * 2;
static constexpr size_t XT_ELEMS = (size_t)NB * 130 * 130 * CIN;
static constexpr size_t WS_NEEDED = XT_OFF + XT_ELEMS * 2;

__device__ __forceinline__ unsigned short f32_bf16(float f) {
  unsigned int x = __float_as_uint(f);
  x += 0x7fffu + ((x >> 16) & 1u);
  return (unsigned short)(x >> 16);
}

__device__ __forceinline__ void gl_lds16(const void* g, void* l) {
  __builtin_amdgcn_global_load_lds((const __attribute__((address_space(1))) void*)g,
                                   (__attribute__((address_space(3))) void*)l, 16, 0, 0);
}

// ---------------- K0: s[b][cin] = style[b] . mod_w[cin] ----------------
__global__ void k_style(const float* __restrict__ style, const float* __restrict__ mod_w,
                        float* __restrict__ s) {
  int b = blockIdx.x, ci = threadIdx.x;
  const float4* st = (const float4*)(style + (size_t)b * SDIM);
  const float4* mw = (const float4*)(mod_w + (size_t)ci * SDIM);
  float acc = 0.f;
  for (int i = 0; i < SDIM / 4; ++i) {
    float4 a = st[i], m = mw[i];
    acc += a.x * m.x + a.y * m.y + a.z * m.z + a.w * m.w;
  }
  s[b * CIN + ci] = acc;
}

// ---------------- K1: demod + wA[b][tap][cout][cin] (bf16) ----------------
__global__ void k_wprep(const float* __restrict__ weight, const float* __restrict__ s,
                        unsigned short* __restrict__ wA) {
  int co = blockIdx.x, b = blockIdx.y, ci = threadIdx.x;
  const float scale = 0.029462782549439483f; // 1/sqrt(128*9)
  float sv = s[b * CIN + ci];
  const float* wp = weight + ((size_t)co * CIN + ci) * 9;
  float u[9], ss = 0.f;
#pragma unroll
  for (int t = 0; t < 9; ++t) { u[t] = scale * wp[t] * sv; ss += u[t] * u[t]; }
#pragma unroll
  for (int off = 32; off; off >>= 1) ss += __shfl_down(ss, off, 64);
  __shared__ float red[2];
  if ((threadIdx.x & 63) == 0) red[threadIdx.x >> 6] = ss;
  __syncthreads();
  float demod = rsqrtf(red[0] + red[1] + 1e-8f);
#pragma unroll
  for (int t = 0; t < 9; ++t)
    wA[((size_t)(b * 9 + t) * COUT + co) * CIN + ci] = f32_bf16(u[t] * demod);
}

// ---------------- K2: xt[b][hb][wb][cin] transpose, halo written in-kernel ----
__global__ void k_xt(const float* __restrict__ x, unsigned short* __restrict__ xt) {
  int hb = blockIdx.x, b = blockIdx.y;
  int t = threadIdx.x;
  unsigned short* orow = xt + ((size_t)b * 130 + hb) * 130 * CIN;
  if (hb == 0 || hb == 129) {
    uint4 z = {0u, 0u, 0u, 0u};
    for (int u = t; u < 2080; u += 256) ((uint4*)orow)[u] = z;
    return;
  }
  __shared__ unsigned short lds[128][132]; // [w][c]
  int h = hb - 1;
  const float* xrow = x + (size_t)b * CIN * HH * WW + (size_t)h * WW;
  for (int i = 0; i < 32; ++i) {
    int flat = i * 256 + t;
    int w = flat & 127, cp = flat >> 7;
    float a0 = xrow[(size_t)(2 * cp) * HH * WW + w];
    float a1 = xrow[(size_t)(2 * cp + 1) * HH * WW + w];
    unsigned int pk = (unsigned int)f32_bf16(a0) | ((unsigned int)f32_bf16(a1) << 16);
    *(unsigned int*)&lds[w][2 * cp] = pk;
  }
  __syncthreads();
  if (t < 32) {
    int side = t >> 4, g = t & 15;
    uint4 z = {0u, 0u, 0u, 0u};
    ((uint4*)(orow + (side ? (size_t)129 * CIN : 0)))[g] = z;
  }
  for (int i = 0; i < 8; ++i) {
    int u = i * 256 + t;
    int w = u >> 4, cg = u & 15;
    uint2 v0 = *(const uint2*)&lds[w][cg * 8];
    uint2 v1 = *(const uint2*)&lds[w][cg * 8 + 4];
    uint4 v = {v0.x, v0.y, v1.x, v1.y};
    *(uint4*)(orow + (size_t)(1 + w) * CIN + cg * 8) = v;
  }
}

// ---------------- K3: conv via 9 shifted GEMMs, 32x32x16 MFMA ----------------
// Block tile = 128 cout x (8 hh x 32 ww): N-dim of the MFMA = ww, so the C/D
// map (col = lane&31 = ww) makes EVERY store instruction write 2 complete
// 128B lines -> out traffic structurally exact, no cross-block line sharing.
// grid (64, NB) b-major, 512 resident blocks (LDS padded 56.3KB -> 2/CU),
// b-span 8. 512 thr = 8 waves (wm = cout half, wn = hh pair); wave = M64 x
// (2hh x 32ww), acc[2][2] f32x16. LDS [row 0..9][g 0..3][col 0..33] 16B units,
// source-permuted staging (r11-validated); B-read lane stride 16B conflict-free.
// C/D map HW-verified (m74/m101): col=lane&31, row=(r&3)+8*(r>>2)+4*(lane>>5).
__launch_bounds__(512, 4)
__global__ void k_conv(const unsigned short* __restrict__ xt,
                       const unsigned short* __restrict__ wA,
                       const float* __restrict__ noise,
                       const float* __restrict__ nw,
                       float* __restrict__ out) {
  __shared__ uint4 ldsraw[2][1760]; // 10*4*34 = 1360 used/buffer; pad -> 56.3KB
  int b = blockIdx.y;
  int tile = blockIdx.x;               // 16 hbands x 4 wbands
  int th = (tile >> 2) * 8, tw = (tile & 3) * 32;
  int t = threadIdx.x;
  int lane = t & 63, wv = t >> 6;
  int wm = wv >> 2, wn = wv & 3;       // wm: cout 64-half, wn: hh pair index
  int l31 = lane & 31, hi = lane >> 5; // l31: A-row / B-col(ww); hi: k-group

  f32x16 acc[2][2]; // [mt][nt]
#pragma unroll
  for (int mt = 0; mt < 2; ++mt)
#pragma unroll
    for (int nt = 0; nt < 2; ++nt)
#pragma unroll
      for (int r = 0; r < 16; ++r) acc[mt][nt][r] = 0.f;

  const unsigned short* xtile = xt + ((size_t)b * 130 + th) * 130 * CIN + (size_t)tw * CIN;
  const unsigned short* wbase = wA + (size_t)b * 9 * COUT * CIN
                                + (size_t)(wm * 64 + l31) * CIN + hi * 8;

  // staging source offsets for [row][g][col] layout:
  // unit u = (row*4+g)*34 + col holds cell (row,col), cin-group g
  int goff[3];
#pragma unroll
  for (int i = 0; i < 3; ++i) {
    int u = i * 512 + t;
    int row = u / 136, rem = u - row * 136;
    int g = rem / 34, col = rem - g * 34;
    goff[i] = (row * 130 + col) * CIN + g * 8;
  }
  int ldsslot = wv * 64;

  auto STAGE = [&](int bb, int q) {
    const unsigned short* xq = xtile + q * 32;
#pragma unroll
    for (int i = 0; i < 3; ++i) {
      int u = i * 512 + t;
      if (u < 1360)
        gl_lds16(xq + goff[i], &ldsraw[bb][i * 512 + ldsslot]);
    }
  };

  STAGE(0, 0);
  __syncthreads();

  for (int q = 0; q < 4; ++q) {
    if (q < 3) STAGE((q + 1) & 1, q + 1); // issue next-chunk x loads BEFORE compute
    const bf16x8* bb_lds = (const bf16x8*)&ldsraw[q & 1][0];
    const unsigned short* wq = wbase + (size_t)q * 32;
#pragma unroll
    for (int ky = 0; ky < 3; ++ky) {
#pragma unroll
      for (int kx = 0; kx < 3; ++kx) {
        int tap = ky * 3 + kx;
        const unsigned short* wt = wq + (size_t)tap * COUT * CIN;
        // A frags [mt][ks]: row = wm*64 + mt*32 + l31, k = ks*16 + hi*8
        bf16x8 a00 = *(const bf16x8*)(wt);
        bf16x8 a01 = *(const bf16x8*)(wt + 16);
        bf16x8 a10 = *(const bf16x8*)(wt + 32 * CIN);
        bf16x8 a11 = *(const bf16x8*)(wt + 32 * CIN + 16);
        // B frags [nt][ks]: cell row = wn*2+nt+ky, col = l31+kx, g = ks*2+hi
        int r0 = wn * 2 + ky;
        int c0 = l31 + kx;
        bf16x8 b00 = bb_lds[((r0)     * 4 + hi)     * 34 + c0];
        bf16x8 b01 = bb_lds[((r0)     * 4 + 2 + hi) * 34 + c0];
        bf16x8 b10 = bb_lds[((r0 + 1) * 4 + hi)     * 34 + c0];
        bf16x8 b11 = bb_lds[((r0 + 1) * 4 + 2 + hi) * 34 + c0];
        acc[0][0] = __builtin_amdgcn_mfma_f32_32x32x16_bf16(a00, b00, acc[0][0], 0, 0, 0);
        acc[0][0] = __builtin_amdgcn_mfma_f32_32x32x16_bf16(a01, b01, acc[0][0], 0, 0, 0);
        acc[0][1] = __builtin_amdgcn_mfma_f32_32x32x16_bf16(a00, b10, acc[0][1], 0, 0, 0);
        acc[0][1] = __builtin_amdgcn_mfma_f32_32x32x16_bf16(a01, b11, acc[0][1], 0, 0, 0);
        acc[1][0] = __builtin_amdgcn_mfma_f32_32x32x16_bf16(a10, b00, acc[1][0], 0, 0, 0);
        acc[1][0] = __builtin_amdgcn_mfma_f32_32x32x16_bf16(a11, b01, acc[1][0], 0, 0, 0);
        acc[1][1] = __builtin_amdgcn_mfma_f32_32x32x16_bf16(a10, b10, acc[1][1], 0, 0, 0);
        acc[1][1] = __builtin_amdgcn_mfma_f32_32x32x16_bf16(a11, b11, acc[1][1], 0, 0, 0);
      }
    }
    __syncthreads();
  }

  // ---- epilogue: each store instruction = 2 FULL 128B lines ----
#pragma unroll
  for (int nt = 0; nt < 2; ++nt) {
    int hh = th + wn * 2 + nt;
    float nv = noise[((size_t)b * HH + hh) * WW + tw + l31];
#pragma unroll
    for (int mt = 0; mt < 2; ++mt) {
#pragma unroll
      for (int r = 0; r < 16; ++r) {
        int cout = wm * 64 + mt * 32 + (r & 3) + 8 * (r >> 2) + 4 * hi;
        out[(((size_t)b * COUT + cout) * HH + hh) * WW + tw + l31] =
            acc[mt][nt][r] + nw[cout] * nv;
      }
    }
  }
}

extern "C" void kernel_launch(void* const* d_in, const int* in_sizes, int n_in,
                              void* d_out, int out_size, void* d_ws, size_t ws_size,
                              hipStream_t stream) {
  const float* x      = (const float*)d_in[0];
  const float* style  = (const float*)d_in[1];
  const float* noise  = (const float*)d_in[2];
  const float* weight = (const float*)d_in[3];
  const float* mod_w  = (const float*)d_in[4];
  const float* nw     = (const float*)d_in[5];
  float* out = (float*)d_out;
  char* ws = (char*)d_ws;
  if (ws_size < WS_NEEDED) return;

  float* s = (float*)ws;
  unsigned short* wA = (unsigned short*)(ws + WA_OFF);
  unsigned short* xt = (unsigned short*)(ws + XT_OFF);

  k_style<<<dim3(NB), dim3(CIN), 0, stream>>>(style, mod_w, s);
  k_wprep<<<dim3(COUT, NB), dim3(CIN), 0, stream>>>(weight, s, wA);
  k_xt<<<dim3(130, NB), dim3(256), 0, stream>>>(x, xt);
  k_conv<<<dim3(64, NB), dim3(512), 0, stream>>>(xt, wA, noise, nw, out);
}

// Round 14
// 236.678 us; speedup vs baseline: 1.1952x; 1.1679x over previous
//
#include <hip/hip_runtime.h>
#include <math.h>

#define NB 16
#define CIN 128
#define COUT 128
#define SDIM 512
#define HH 128
#define WW 128

typedef __bf16 bf16x8 __attribute__((ext_vector_type(8)));
typedef float f32x16 __attribute__((ext_vector_type(16)));

static constexpr size_t WA_OFF = 8192;                          // after s (2048 f32)
static constexpr size_t WA_ELEMS = (size_t)NB * 9 * COUT * CIN; // 2,359,296 bf16
static constexpr size_t XT_OFF = WA_OFF + WA_ELEMS * 2;
static constexpr size_t XT_ELEMS = (size_t)NB * 130 * 130 * CIN;
static constexpr size_t WS_NEEDED = XT_OFF + XT_ELEMS * 2;

__device__ __forceinline__ unsigned short f32_bf16(float f) {
  unsigned int x = __float_as_uint(f);
  x += 0x7fffu + ((x >> 16) & 1u);
  return (unsigned short)(x >> 16);
}

__device__ __forceinline__ void gl_lds16(const void* g, void* l) {
  __builtin_amdgcn_global_load_lds((const __attribute__((address_space(1))) void*)g,
                                   (__attribute__((address_space(3))) void*)l, 16, 0, 0);
}

// ---------------- K0: s[b][cin] = style[b] . mod_w[cin] ----------------
__global__ void k_style(const float* __restrict__ style, const float* __restrict__ mod_w,
                        float* __restrict__ s) {
  int b = blockIdx.x, ci = threadIdx.x;
  const float4* st = (const float4*)(style + (size_t)b * SDIM);
  const float4* mw = (const float4*)(mod_w + (size_t)ci * SDIM);
  float acc = 0.f;
  for (int i = 0; i < SDIM / 4; ++i) {
    float4 a = st[i], m = mw[i];
    acc += a.x * m.x + a.y * m.y + a.z * m.z + a.w * m.w;
  }
  s[b * CIN + ci] = acc;
}

// ---------------- K1: demod + wA[b][tap][cout][cin] (bf16) ----------------
__global__ void k_wprep(const float* __restrict__ weight, const float* __restrict__ s,
                        unsigned short* __restrict__ wA) {
  int co = blockIdx.x, b = blockIdx.y, ci = threadIdx.x;
  const float scale = 0.029462782549439483f; // 1/sqrt(128*9)
  float sv = s[b * CIN + ci];
  const float* wp = weight + ((size_t)co * CIN + ci) * 9;
  float u[9], ss = 0.f;
#pragma unroll
  for (int t = 0; t < 9; ++t) { u[t] = scale * wp[t] * sv; ss += u[t] * u[t]; }
#pragma unroll
  for (int off = 32; off; off >>= 1) ss += __shfl_down(ss, off, 64);
  __shared__ float red[2];
  if ((threadIdx.x & 63) == 0) red[threadIdx.x >> 6] = ss;
  __syncthreads();
  float demod = rsqrtf(red[0] + red[1] + 1e-8f);
#pragma unroll
  for (int t = 0; t < 9; ++t)
    wA[((size_t)(b * 9 + t) * COUT + co) * CIN + ci] = f32_bf16(u[t] * demod);
}

// ---------------- K2: xt[b][hb][wb][cin] transpose, halo written in-kernel ----
__global__ void k_xt(const float* __restrict__ x, unsigned short* __restrict__ xt) {
  int hb = blockIdx.x, b = blockIdx.y;
  int t = threadIdx.x;
  unsigned short* orow = xt + ((size_t)b * 130 + hb) * 130 * CIN;
  if (hb == 0 || hb == 129) {
    uint4 z = {0u, 0u, 0u, 0u};
    for (int u = t; u < 2080; u += 256) ((uint4*)orow)[u] = z;
    return;
  }
  __shared__ unsigned short lds[128][132]; // [w][c]
  int h = hb - 1;
  const float* xrow = x + (size_t)b * CIN * HH * WW + (size_t)h * WW;
  for (int i = 0; i < 32; ++i) {
    int flat = i * 256 + t;
    int w = flat & 127, cp = flat >> 7;
    float a0 = xrow[(size_t)(2 * cp) * HH * WW + w];
    float a1 = xrow[(size_t)(2 * cp + 1) * HH * WW + w];
    unsigned int pk = (unsigned int)f32_bf16(a0) | ((unsigned int)f32_bf16(a1) << 16);
    *(unsigned int*)&lds[w][2 * cp] = pk;
  }
  __syncthreads();
  if (t < 32) {
    int side = t >> 4, g = t & 15;
    uint4 z = {0u, 0u, 0u, 0u};
    ((uint4*)(orow + (side ? (size_t)129 * CIN : 0)))[g] = z;
  }
  for (int i = 0; i < 8; ++i) {
    int u = i * 256 + t;
    int w = u >> 4, cg = u & 15;
    uint2 v0 = *(const uint2*)&lds[w][cg * 8];
    uint2 v1 = *(const uint2*)&lds[w][cg * 8 + 4];
    uint4 v = {v0.x, v0.y, v1.x, v1.y};
    *(uint4*)(orow + (size_t)(1 + w) * CIN + cg * 8) = v;
  }
}

// ---------------- K3: conv, BARRIER-FREE per-wave pipeline ----------------
// 4 independent waves/block (wm: cout half, wn: hh pair); wave tile =
// 64 cout x 2 hh x 32 ww via 32x32x16 MFMA (acc[2][2] f32x16).
// Each wave owns a PRIVATE LDS double-buffer (4 rows x 4 g x 34 cols, 16B
// units) staged by global_load_lds; sync = counted s_waitcnt vmcnt(9)
// (the 9 next-buffer staging ops), lgkmcnt(0) before overwrite, sched_barrier
// fences (rule #18). NO __syncthreads anywhere -> no barrier drain, no
// inter-wave coupling. LDS 69.6KB/block -> 2 blocks/CU = 8 waves/CU (the
// proven exact-memory envelope; 512 resident blocks span 4 batches).
// Stores: full 2x128B lines per instruction (r13-validated C/D map).
__launch_bounds__(256, 2)
__global__ void k_conv(const unsigned short* __restrict__ xt,
                       const unsigned short* __restrict__ wA,
                       const float* __restrict__ noise,
                       const float* __restrict__ nw,
                       float* __restrict__ out) {
  __shared__ uint4 lds[4][2][544]; // [wave][dbuf][(row*4+g)*34+col]
  int b = blockIdx.y;
  int tile = blockIdx.x;               // 32 hbands x 4 wbands
  int th = (tile >> 2) * 4, tw = (tile & 3) * 32;
  int t = threadIdx.x;
  int lane = t & 63, wv = t >> 6;
  int wm = wv >> 1, wn = wv & 1;
  int l31 = lane & 31, hi = lane >> 5;

  f32x16 acc[2][2]; // [mt][nt]
#pragma unroll
  for (int mt = 0; mt < 2; ++mt)
#pragma unroll
    for (int nt = 0; nt < 2; ++nt)
#pragma unroll
      for (int r = 0; r < 16; ++r) acc[mt][nt][r] = 0.f;

  // wave's xt window: rows th+wn*2 .. +3, cols tw .. tw+33
  const unsigned short* xwave = xt + ((size_t)b * 130 + th + wn * 2) * 130 * CIN
                                + (size_t)tw * CIN;
  const unsigned short* wbase = wA + (size_t)b * 9 * COUT * CIN
                                + (size_t)(wm * 64 + l31) * CIN + hi * 8;

  // staging source offsets: unit u = (row*4+g)*34+col -> xt (row, col, g)
  int goff[9];
#pragma unroll
  for (int i = 0; i < 9; ++i) {
    int u = i * 64 + lane;
    int row = u / 136, rem = u - row * 136;
    int g = rem / 34, col = rem - g * 34;
    goff[i] = (row * 130 + col) * CIN + g * 8;
  }

  auto STAGE = [&](int bb, int q) {
    const unsigned short* xq = xwave + q * 32;
    uint4* dst = &lds[wv][bb][0];
#pragma unroll
    for (int i = 0; i < 9; ++i) {
      int u = i * 64 + lane;
      if (u < 544) gl_lds16(xq + goff[i], dst + i * 64);
    }
  };

  STAGE(0, 0);

  for (int q = 0; q < 4; ++q) {
    // all ds_reads of the buffer we are about to overwrite have retired:
    asm volatile("s_waitcnt lgkmcnt(0)" ::: "memory");
    __builtin_amdgcn_sched_barrier(0);
    if (q < 3) STAGE((q + 1) & 1, q + 1); // 9 vm ops in flight for next buf
    __builtin_amdgcn_sched_barrier(0);
    if (q < 3) { asm volatile("s_waitcnt vmcnt(9)" ::: "memory"); }
    else       { asm volatile("s_waitcnt vmcnt(0)" ::: "memory"); }
    __builtin_amdgcn_sched_barrier(0);   // rule #18: pin reads below the wait

    const bf16x8* myl = (const bf16x8*)&lds[wv][q & 1][0];
    const unsigned short* wq = wbase + (size_t)q * 32;

    bf16x8 afA[4], afB[4]; // [mt*2+ks], 1-tap-ahead rotation
#pragma unroll
    for (int mt = 0; mt < 2; ++mt)
#pragma unroll
      for (int ks = 0; ks < 2; ++ks)
        afA[mt * 2 + ks] = *(const bf16x8*)(wq + (size_t)mt * 32 * CIN + ks * 16);

    auto TAPBODY = [&](int tap, bf16x8 (&cur)[4], bf16x8 (&nxt)[4]) {
      if (tap < 8) {
        const unsigned short* wt = wq + (size_t)(tap + 1) * COUT * CIN;
#pragma unroll
        for (int mt = 0; mt < 2; ++mt)
#pragma unroll
          for (int ks = 0; ks < 2; ++ks)
            nxt[mt * 2 + ks] = *(const bf16x8*)(wt + (size_t)mt * 32 * CIN + ks * 16);
      }
      int ky = tap / 3, kx = tap - 3 * (tap / 3);
#pragma unroll
      for (int nt = 0; nt < 2; ++nt) {
#pragma unroll
        for (int ks = 0; ks < 2; ++ks) {
          bf16x8 bv = myl[((nt + ky) * 4 + ks * 2 + hi) * 34 + l31 + kx];
          acc[0][nt] = __builtin_amdgcn_mfma_f32_32x32x16_bf16(cur[ks],     bv, acc[0][nt], 0, 0, 0);
          acc[1][nt] = __builtin_amdgcn_mfma_f32_32x32x16_bf16(cur[2 + ks], bv, acc[1][nt], 0, 0, 0);
        }
      }
    };

    TAPBODY(0, afA, afB);
    TAPBODY(1, afB, afA);
    TAPBODY(2, afA, afB);
    TAPBODY(3, afB, afA);
    TAPBODY(4, afA, afB);
    TAPBODY(5, afB, afA);
    TAPBODY(6, afA, afB);
    TAPBODY(7, afB, afA);
    TAPBODY(8, afA, afB);
  }

  // ---- epilogue: each store instruction writes 2 FULL 128B lines ----
#pragma unroll
  for (int nt = 0; nt < 2; ++nt) {
    int hh = th + wn * 2 + nt;
    float nv = noise[((size_t)b * HH + hh) * WW + tw + l31];
#pragma unroll
    for (int mt = 0; mt < 2; ++mt) {
#pragma unroll
      for (int r = 0; r < 16; ++r) {
        int cout = wm * 64 + mt * 32 + (r & 3) + 8 * (r >> 2) + 4 * hi;
        out[(((size_t)b * COUT + cout) * HH + hh) * WW + tw + l31] =
            acc[mt][nt][r] + nw[cout] * nv;
      }
    }
  }
}

extern "C" void kernel_launch(void* const* d_in, const int* in_sizes, int n_in,
                              void* d_out, int out_size, void* d_ws, size_t ws_size,
                              hipStream_t stream) {
  const float* x      = (const float*)d_in[0];
  const float* style  = (const float*)d_in[1];
  const float* noise  = (const float*)d_in[2];
  const float* weight = (const float*)d_in[3];
  const float* mod_w  = (const float*)d_in[4];
  const float* nw     = (const float*)d_in[5];
  float* out = (float*)d_out;
  char* ws = (char*)d_ws;
  if (ws_size < WS_NEEDED) return;

  float* s = (float*)ws;
  unsigned short* wA = (unsigned short*)(ws + WA_OFF);
  unsigned short* xt = (unsigned short*)(ws + XT_OFF);

  k_style<<<dim3(NB), dim3(CIN), 0, stream>>>(style, mod_w, s);
  k_wprep<<<dim3(COUT, NB), dim3(CIN), 0, stream>>>(weight, s, wA);
  k_xt<<<dim3(130, NB), dim3(256), 0, stream>>>(x, xt);
  k_conv<<<dim3(128, NB), dim3(256), 0, stream>>>(xt, wA, noise, nw, out);
}

// Round 15
// 220.769 us; speedup vs baseline: 1.2813x; 1.0721x over previous
//
#include <hip/hip_runtime.h>
#include <math.h>

#define NB 16
#define CIN 128
#define COUT 128
#define SDIM 512
#define HH 128
#define WW 128

typedef __bf16 bf16x8 __attribute__((ext_vector_type(8)));
typedef float f32x16 __attribute__((ext_vector_type(16)));

static constexpr size_t WA_OFF = 8192;                          // after s (2048 f32)
static constexpr size_t WA_ELEMS = (size_t)NB * 9 * COUT * CIN; // 2,359,296 bf16
static constexpr size_t XT_OFF = WA_OFF + WA_ELEMS * 2;
static constexpr size_t XT_ELEMS = (size_t)NB * 130 * 130 * CIN;
static constexpr size_t WS_NEEDED = XT_OFF + XT_ELEMS * 2;

__device__ __forceinline__ unsigned short f32_bf16(float f) {
  unsigned int x = __float_as_uint(f);
  x += 0x7fffu + ((x >> 16) & 1u);
  return (unsigned short)(x >> 16);
}

__device__ __forceinline__ void gl_lds16(const void* g, void* l) {
  __builtin_amdgcn_global_load_lds((const __attribute__((address_space(1))) void*)g,
                                   (__attribute__((address_space(3))) void*)l, 16, 0, 0);
}

// ---------------- K0: s[b][cin] = style[b] . mod_w[cin] ----------------
__global__ void k_style(const float* __restrict__ style, const float* __restrict__ mod_w,
                        float* __restrict__ s) {
  int b = blockIdx.x, ci = threadIdx.x;
  const float4* st = (const float4*)(style + (size_t)b * SDIM);
  const float4* mw = (const float4*)(mod_w + (size_t)ci * SDIM);
  float acc = 0.f;
  for (int i = 0; i < SDIM / 4; ++i) {
    float4 a = st[i], m = mw[i];
    acc += a.x * m.x + a.y * m.y + a.z * m.z + a.w * m.w;
  }
  s[b * CIN + ci] = acc;
}

// ---------------- K1: demod + wA[b][tap][cout][cin] (bf16) ----------------
__global__ void k_wprep(const float* __restrict__ weight, const float* __restrict__ s,
                        unsigned short* __restrict__ wA) {
  int co = blockIdx.x, b = blockIdx.y, ci = threadIdx.x;
  const float scale = 0.029462782549439483f; // 1/sqrt(128*9)
  float sv = s[b * CIN + ci];
  const float* wp = weight + ((size_t)co * CIN + ci) * 9;
  float u[9], ss = 0.f;
#pragma unroll
  for (int t = 0; t < 9; ++t) { u[t] = scale * wp[t] * sv; ss += u[t] * u[t]; }
#pragma unroll
  for (int off = 32; off; off >>= 1) ss += __shfl_down(ss, off, 64);
  __shared__ float red[2];
  if ((threadIdx.x & 63) == 0) red[threadIdx.x >> 6] = ss;
  __syncthreads();
  float demod = rsqrtf(red[0] + red[1] + 1e-8f);
#pragma unroll
  for (int t = 0; t < 9; ++t)
    wA[((size_t)(b * 9 + t) * COUT + co) * CIN + ci] = f32_bf16(u[t] * demod);
}

// ---------------- K2: xt[b][hb][wb][cin] transpose, halo written in-kernel ----
__global__ void k_xt(const float* __restrict__ x, unsigned short* __restrict__ xt) {
  int hb = blockIdx.x, b = blockIdx.y;
  int t = threadIdx.x;
  unsigned short* orow = xt + ((size_t)b * 130 + hb) * 130 * CIN;
  if (hb == 0 || hb == 129) {
    uint4 z = {0u, 0u, 0u, 0u};
    for (int u = t; u < 2080; u += 256) ((uint4*)orow)[u] = z;
    return;
  }
  __shared__ unsigned short lds[128][132]; // [w][c]
  int h = hb - 1;
  const float* xrow = x + (size_t)b * CIN * HH * WW + (size_t)h * WW;
  for (int i = 0; i < 32; ++i) {
    int flat = i * 256 + t;
    int w = flat & 127, cp = flat >> 7;
    float a0 = xrow[(size_t)(2 * cp) * HH * WW + w];
    float a1 = xrow[(size_t)(2 * cp + 1) * HH * WW + w];
    unsigned int pk = (unsigned int)f32_bf16(a0) | ((unsigned int)f32_bf16(a1) << 16);
    *(unsigned int*)&lds[w][2 * cp] = pk;
  }
  __syncthreads();
  if (t < 32) {
    int side = t >> 4, g = t & 15;
    uint4 z = {0u, 0u, 0u, 0u};
    ((uint4*)(orow + (side ? (size_t)129 * CIN : 0)))[g] = z;
  }
  for (int i = 0; i < 8; ++i) {
    int u = i * 256 + t;
    int w = u >> 4, cg = u & 15;
    uint2 v0 = *(const uint2*)&lds[w][cg * 8];
    uint2 v1 = *(const uint2*)&lds[w][cg * 8 + 4];
    uint4 v = {v0.x, v0.y, v1.x, v1.y};
    *(uint4*)(orow + (size_t)(1 + w) * CIN + cg * 8) = v;
  }
}

// ---------------- K3: conv via 9 shifted GEMMs, 32x32x16 MFMA ----------------
// r9 block-cooperative shell x r12/r13 MFMA shape, pinned at the clean-memory
// occupancy ceiling: 3 blocks/CU = 12 waves/CU = 3 waves/SIMD (LDS padded to
// 50KB). Block = 256 thr / 4 waves (wm: cout half, wn: hh pair); block tile =
// 128 cout x 4 hh x 32 ww; wave = M64 x (2hh x 32ww), acc[2][2] f32x16.
// grid (128, NB) b-major -> 768 resident blocks span 6 batches (clean, r10).
// One __syncthreads per cin-chunk; dbuf global_load_lds staging ([row][g][col]
// source-permuted, B-read lane stride 16B conflict-free); 1-tap-ahead A
// register rotation. Stores: full 2x128B lines per instruction (r13 map).
__launch_bounds__(256, 3)
__global__ void k_conv(const unsigned short* __restrict__ xt,
                       const unsigned short* __restrict__ wA,
                       const float* __restrict__ noise,
                       const float* __restrict__ nw,
                       float* __restrict__ out) {
  __shared__ uint4 ldsraw[2][1600]; // 6*4*34 = 816 used/buffer; pad -> 50KB
  int b = blockIdx.y;
  int tile = blockIdx.x;               // 32 hbands x 4 wbands
  int th = (tile >> 2) * 4, tw = (tile & 3) * 32;
  int t = threadIdx.x;
  int lane = t & 63, wv = t >> 6;
  int wm = wv >> 1, wn = wv & 1;       // wm: cout 64-half, wn: hh pair
  int l31 = lane & 31, hi = lane >> 5; // l31: A-row / B-col(ww); hi: k-group

  f32x16 acc[2][2]; // [mt][nt]
#pragma unroll
  for (int mt = 0; mt < 2; ++mt)
#pragma unroll
    for (int nt = 0; nt < 2; ++nt)
#pragma unroll
      for (int r = 0; r < 16; ++r) acc[mt][nt][r] = 0.f;

  const unsigned short* xtile = xt + ((size_t)b * 130 + th) * 130 * CIN + (size_t)tw * CIN;
  const unsigned short* wbase = wA + (size_t)b * 9 * COUT * CIN
                                + (size_t)(wm * 64 + l31) * CIN + hi * 8;

  // staging source offsets for [row 0..5][g 0..3][col 0..33] layout:
  // unit u = (row*4+g)*34 + col holds cell (row,col), cin-group g
  int goff[4];
#pragma unroll
  for (int i = 0; i < 4; ++i) {
    int u = i * 256 + t;
    int row = u / 136, rem = u - row * 136;
    int g = rem / 34, col = rem - g * 34;
    goff[i] = (row * 130 + col) * CIN + g * 8;
  }

  auto STAGE = [&](int bb, int q) {
    const unsigned short* xq = xtile + q * 32;
    uint4* dst = &ldsraw[bb][0];
#pragma unroll
    for (int i = 0; i < 4; ++i) {
      int u = i * 256 + t;
      if (u < 816) gl_lds16(xq + goff[i], dst + u);
    }
  };

  STAGE(0, 0);
  __syncthreads();

  for (int q = 0; q < 4; ++q) {
    if (q < 3) STAGE((q + 1) & 1, q + 1); // issue next-chunk loads BEFORE compute
    const bf16x8* myl = (const bf16x8*)&ldsraw[q & 1][0];
    const unsigned short* wq = wbase + (size_t)q * 32;

    bf16x8 afA[4], afB[4]; // [mt*2+ks], 1-tap-ahead rotation
#pragma unroll
    for (int mt = 0; mt < 2; ++mt)
#pragma unroll
      for (int ks = 0; ks < 2; ++ks)
        afA[mt * 2 + ks] = *(const bf16x8*)(wq + (size_t)mt * 32 * CIN + ks * 16);

    auto TAPBODY = [&](int tap, bf16x8 (&cur)[4], bf16x8 (&nxt)[4]) {
      if (tap < 8) {
        const unsigned short* wt = wq + (size_t)(tap + 1) * COUT * CIN;
#pragma unroll
        for (int mt = 0; mt < 2; ++mt)
#pragma unroll
          for (int ks = 0; ks < 2; ++ks)
            nxt[mt * 2 + ks] = *(const bf16x8*)(wt + (size_t)mt * 32 * CIN + ks * 16);
      }
      int ky = tap / 3, kx = tap - 3 * (tap / 3);
#pragma unroll
      for (int nt = 0; nt < 2; ++nt) {
        int row0 = wn * 2 + nt + ky;       // 0..5
        int c0 = l31 + kx;                 // 0..33
#pragma unroll
        for (int ks = 0; ks < 2; ++ks) {
          bf16x8 bv = myl[((size_t)(row0 * 4 + ks * 2 + hi)) * 34 + c0];
          acc[0][nt] = __builtin_amdgcn_mfma_f32_32x32x16_bf16(cur[ks],     bv, acc[0][nt], 0, 0, 0);
          acc[1][nt] = __builtin_amdgcn_mfma_f32_32x32x16_bf16(cur[2 + ks], bv, acc[1][nt], 0, 0, 0);
        }
      }
    };

    TAPBODY(0, afA, afB);
    TAPBODY(1, afB, afA);
    TAPBODY(2, afA, afB);
    TAPBODY(3, afB, afA);
    TAPBODY(4, afA, afB);
    TAPBODY(5, afB, afA);
    TAPBODY(6, afA, afB);
    TAPBODY(7, afB, afA);
    TAPBODY(8, afA, afB);

    __syncthreads();
  }

  // ---- epilogue: each store instruction writes 2 FULL 128B lines ----
#pragma unroll
  for (int nt = 0; nt < 2; ++nt) {
    int hh = th + wn * 2 + nt;
    float nv = noise[((size_t)b * HH + hh) * WW + tw + l31];
#pragma unroll
    for (int mt = 0; mt < 2; ++mt) {
#pragma unroll
      for (int r = 0; r < 16; ++r) {
        int cout = wm * 64 + mt * 32 + (r & 3) + 8 * (r >> 2) + 4 * hi;
        out[(((size_t)b * COUT + cout) * HH + hh) * WW + tw + l31] =
            acc[mt][nt][r] + nw[cout] * nv;
      }
    }
  }
}

extern "C" void kernel_launch(void* const* d_in, const int* in_sizes, int n_in,
                              void* d_out, int out_size, void* d_ws, size_t ws_size,
                              hipStream_t stream) {
  const float* x      = (const float*)d_in[0];
  const float* style  = (const float*)d_in[1];
  const float* noise  = (const float*)d_in[2];
  const float* weight = (const float*)d_in[3];
  const float* mod_w  = (const float*)d_in[4];
  const float* nw     = (const float*)d_in[5];
  float* out = (float*)d_out;
  char* ws = (char*)d_ws;
  if (ws_size < WS_NEEDED) return;

  float* s = (float*)ws;
  unsigned short* wA = (unsigned short*)(ws + WA_OFF);
  unsigned short* xt = (unsigned short*)(ws + XT_OFF);

  k_style<<<dim3(NB), dim3(CIN), 0, stream>>>(style, mod_w, s);
  k_wprep<<<dim3(COUT, NB), dim3(CIN), 0, stream>>>(weight, s, wA);
  k_xt<<<dim3(130, NB), dim3(256), 0, stream>>>(x, xt);
  k_conv<<<dim3(128, NB), dim3(256), 0, stream>>>(xt, wA, noise, nw, out);
}